// Round 4
// baseline (793.623 us; speedup 1.0000x reference)
//
#include <hip/hip_runtime.h>
#include <hip/hip_bf16.h>

typedef unsigned short u16;
typedef unsigned int   u32;
typedef _Float16 half8 __attribute__((ext_vector_type(8)));
typedef __attribute__((ext_vector_type(4))) float f32x4;

constexpr int NB = 4;        // batch
constexpr int S  = 4096;     // sequence
constexpr int D  = 1024;     // model dim
constexpr int BK = 32;       // GEMM K-tile (one mfma_16x16x32 per frag pair)

__device__ __forceinline__ u16 h2u(_Float16 h) {
    union { _Float16 h; u16 u; } v; v.h = h; return v.u;
}
__device__ __forceinline__ _Float16 u2h(u16 u) {
    union { u16 u; _Float16 h; } v; v.u = u; return v.h;
}

// Load 8 source elements as fp16x8. F32 path converts fp32->fp16 (RNE).
template<bool F32>
__device__ __forceinline__ half8 load8(const char* p) {
    if constexpr (F32) {
        const float* f = (const float*)p;
        float4 lo = *(const float4*)f;
        float4 hi = *(const float4*)(f + 4);
        half8 r;
        r[0] = (_Float16)lo.x; r[1] = (_Float16)lo.y;
        r[2] = (_Float16)lo.z; r[3] = (_Float16)lo.w;
        r[4] = (_Float16)hi.x; r[5] = (_Float16)hi.y;
        r[6] = (_Float16)hi.z; r[7] = (_Float16)hi.w;
        return r;
    } else {
        return *(const half8*)p;
    }
}

// ---------------------------------------------------------------------------
// NT GEMM core: A [128 rows x K] (pre-offset to tile), B [128 x K], both
// row-major with element type fp32 (F32SRC=true) or fp16 (false). Computes
// 128x128 tile into acc via 16x16x32 f16 MFMA. 256 threads = 4 waves (2x2),
// each wave 64x64 (4x4 mfma tiles).
// Fragment layouts (HW-verified per guide, dtype-independent):
//   A: lane holds A[m=lane&15][k0 + (lane>>4)*8 + j]
//   B: lane holds B[n=lane&15][k0 + (lane>>4)*8 + j]
//   C: acc[r] = C[row=(lane>>4)*4+r][col=lane&15]
// ---------------------------------------------------------------------------
template<bool F32SRC>
__device__ __forceinline__ void gemm_nt_core(
    const void* __restrict__ Av, const void* __restrict__ Bvp, int K,
    u16* As, u16* Bs, f32x4 acc[4][4])
{
    const int tid  = threadIdx.x;
    const int lane = tid & 63;
    const int wid  = tid >> 6;
    const int quad = lane >> 4;
    const int lrow = lane & 15;
    const int wm   = (wid & 1) * 64;
    const int wn   = (wid >> 1) * 64;

    constexpr size_t esz = F32SRC ? 4 : 2;

    // staging: 512 vec8 segments per matrix per tile; thread does 2 (rows sr, sr+64)
    const int sr = tid >> 2;            // 0..63
    const int sc = (tid & 3) * 8;       // 0,8,16,24

    const char* Ap0 = (const char*)Av  + ((size_t)sr * K + sc) * esz;
    const char* Ap1 = Ap0 + (size_t)64 * K * esz;
    const char* Bp0 = (const char*)Bvp + ((size_t)sr * K + sc) * esz;
    const char* Bp1 = Bp0 + (size_t)64 * K * esz;

    u16* AsW0 = As + sr * BK + sc;  u16* AsW1 = AsW0 + 64 * BK;
    u16* BsW0 = Bs + sr * BK + sc;  u16* BsW1 = BsW0 + 64 * BK;

    const u16* AsR = As + (size_t)(wm + lrow) * BK + quad * 8;
    const u16* BsR = Bs + (size_t)(wn + lrow) * BK + quad * 8;

    for (int k0 = 0; k0 < K; k0 += BK) {
        const size_t ko = (size_t)k0 * esz;
        half8 a0 = load8<F32SRC>(Ap0 + ko);
        half8 a1 = load8<F32SRC>(Ap1 + ko);
        half8 b0 = load8<F32SRC>(Bp0 + ko);
        half8 b1 = load8<F32SRC>(Bp1 + ko);
        __syncthreads();                 // previous iter done reading LDS
        *(half8*)AsW0 = a0;  *(half8*)AsW1 = a1;
        *(half8*)BsW0 = b0;  *(half8*)BsW1 = b1;
        __syncthreads();
        half8 af[4], bf[4];
#pragma unroll
        for (int i = 0; i < 4; ++i) af[i] = *(const half8*)(AsR + i * 16 * BK);
#pragma unroll
        for (int i = 0; i < 4; ++i) bf[i] = *(const half8*)(BsR + i * 16 * BK);
#pragma unroll
        for (int im = 0; im < 4; ++im)
#pragma unroll
            for (int in = 0; in < 4; ++in)
                acc[im][in] = __builtin_amdgcn_mfma_f32_16x16x32_f16(
                    af[im], bf[in], acc[im][in], 0, 0, 0);
    }
}

// ---------------------------------------------------------------------------
// 1) QKV projection: out[s,e] = sum_d x[s,d] * W[e,d]  (NT, K=D), fp32 src.
// grid (NB*S/128=128, D/128=8, 3); z picks {Wq,Wk,Wv} -> {Q,K,V} (fp16 out)
// ---------------------------------------------------------------------------
__global__ __launch_bounds__(256) void qkv_kernel(
    const float* __restrict__ x, const float* __restrict__ Wq,
    const float* __restrict__ Wk, const float* __restrict__ Wv,
    u16* __restrict__ Q, u16* __restrict__ Kb, u16* __restrict__ V)
{
    __shared__ u16 As[128 * BK];
    __shared__ u16 Bs[128 * BK];
    const int tile_m = blockIdx.x * 128;
    const int tile_n = blockIdx.y * 128;
    const float* W; u16* out;
    if (blockIdx.z == 0)      { W = Wq; out = Q;  }
    else if (blockIdx.z == 1) { W = Wk; out = Kb; }
    else                      { W = Wv; out = V;  }

    f32x4 acc[4][4];
#pragma unroll
    for (int i = 0; i < 4; ++i)
#pragma unroll
        for (int j = 0; j < 4; ++j) acc[i][j] = (f32x4)0.0f;

    gemm_nt_core<true>(x + (size_t)tile_m * D, W + (size_t)tile_n * D, D, As, Bs, acc);

    const int tid = threadIdx.x, lane = tid & 63, wid = tid >> 6;
    const int quad = lane >> 4, lrow = lane & 15;
    const int wm = (wid & 1) * 64, wn = (wid >> 1) * 64;
#pragma unroll
    for (int im = 0; im < 4; ++im)
#pragma unroll
        for (int r = 0; r < 4; ++r) {
            const int row = tile_m + wm + im * 16 + quad * 4 + r;
#pragma unroll
            for (int in = 0; in < 4; ++in) {
                const int col = tile_n + wn + in * 16 + lrow;
                out[(size_t)row * D + col] = h2u((_Float16)acc[im][in][r]);
            }
        }
}

// ---------------------------------------------------------------------------
// 2) Transpose V [NB*S x D] -> Vt [NB][D][S] (64x64 LDS tiles, fp16 bits)
// ---------------------------------------------------------------------------
__global__ __launch_bounds__(256) void transpose_v(
    const u16* __restrict__ V, u16* __restrict__ Vt)
{
    __shared__ u16 t[64][72];                      // 144B row stride (16B-mult)
    const int sg = blockIdx.x * 64;                // global row (b,s)
    const int b  = sg >> 12;
    const int s0 = sg & (S - 1);
    const int e0 = blockIdx.y * 64;
    const int tid = threadIdx.x;
#pragma unroll
    for (int p = 0; p < 2; ++p) {
        const int v  = tid + 256 * p;              // 0..511
        const int sr = v >> 3, sc = (v & 7) * 8;
        half8 vec = *(const half8*)(V + (size_t)(sg + sr) * D + e0 + sc);
        *(half8*)&t[sr][sc] = vec;
    }
    __syncthreads();
#pragma unroll
    for (int p = 0; p < 2; ++p) {
        const int v  = tid + 256 * p;
        const int e  = v >> 3, s8 = (v & 7) * 8;
        u16 o[8];
#pragma unroll
        for (int j = 0; j < 8; ++j) o[j] = t[s8 + j][e];
        *(uint4*)(Vt + (size_t)b * D * S + (size_t)(e0 + e) * S + s0 + s8) = *(const uint4*)o;
    }
}

// ---------------------------------------------------------------------------
// 3) scores: P[b][q][k] = Q_b[q,:] . K_b[k,:]   (NT, K=D), grid (32,32,4)
// ---------------------------------------------------------------------------
__global__ __launch_bounds__(256) void scores_kernel(
    const u16* __restrict__ Q, const u16* __restrict__ Kb, u16* __restrict__ P)
{
    __shared__ u16 As[128 * BK];
    __shared__ u16 Bs[128 * BK];
    const int b = blockIdx.z;
    const int tile_m = blockIdx.x * 128;
    const int tile_n = blockIdx.y * 128;
    const u16* Ab = Q  + (size_t)b * S * D + (size_t)tile_m * D;
    const u16* Bv = Kb + (size_t)b * S * D + (size_t)tile_n * D;

    f32x4 acc[4][4];
#pragma unroll
    for (int i = 0; i < 4; ++i)
#pragma unroll
        for (int j = 0; j < 4; ++j) acc[i][j] = (f32x4)0.0f;

    gemm_nt_core<false>(Ab, Bv, D, As, Bs, acc);

    u16* Pb = P + (size_t)b * S * S;
    const int tid = threadIdx.x, lane = tid & 63, wid = tid >> 6;
    const int quad = lane >> 4, lrow = lane & 15;
    const int wm = (wid & 1) * 64, wn = (wid >> 1) * 64;
#pragma unroll
    for (int im = 0; im < 4; ++im)
#pragma unroll
        for (int r = 0; r < 4; ++r) {
            const int row = tile_m + wm + im * 16 + quad * 4 + r;
#pragma unroll
            for (int in = 0; in < 4; ++in) {
                const int col = tile_n + wn + in * 16 + lrow;
                Pb[(size_t)row * S + col] = h2u((_Float16)acc[im][in][r]);
            }
        }
}

// ---------------------------------------------------------------------------
// 4) softmax over each row of P (4096 fp16), in place. 256 thr x 16 elems.
// ---------------------------------------------------------------------------
__global__ __launch_bounds__(256) void softmax_kernel(u16* __restrict__ P)
{
    const size_t row = blockIdx.x;                 // 0..NB*S-1 (flat: stride S)
    u16* p = P + row * S;
    const int tid = threadIdx.x;

    half8 h0 = *(const half8*)(p + tid * 16);
    half8 h1 = *(const half8*)(p + tid * 16 + 8);
    float v[16];
#pragma unroll
    for (int i = 0; i < 8; ++i) { v[i] = (float)h0[i]; v[8 + i] = (float)h1[i]; }

    float m = v[0];
#pragma unroll
    for (int i = 1; i < 16; ++i) m = fmaxf(m, v[i]);
#pragma unroll
    for (int off = 32; off > 0; off >>= 1) m = fmaxf(m, __shfl_xor(m, off));

    __shared__ float redm[4], reds[4];
    const int wid = tid >> 6;
    if ((tid & 63) == 0) redm[wid] = m;
    __syncthreads();
    m = fmaxf(fmaxf(redm[0], redm[1]), fmaxf(redm[2], redm[3]));

    float e[16], s = 0.f;
#pragma unroll
    for (int i = 0; i < 16; ++i) { e[i] = __expf(v[i] - m); s += e[i]; }
#pragma unroll
    for (int off = 32; off > 0; off >>= 1) s += __shfl_xor(s, off);
    if ((tid & 63) == 0) reds[wid] = s;
    __syncthreads();
    s = reds[0] + reds[1] + reds[2] + reds[3];
    const float inv = 1.0f / s;                    // s >= 1 always

#pragma unroll
    for (int i = 0; i < 8; ++i) {
        h0[i] = (_Float16)(e[i] * inv);
        h1[i] = (_Float16)(e[8 + i] * inv);
    }
    *(half8*)(p + tid * 16)     = h0;
    *(half8*)(p + tid * 16 + 8) = h1;
}

// ---------------------------------------------------------------------------
// 5) PV: y[b,q,d] = sum_k P[b,q,k]*Vt[b,d,k] + x[b,q,d]; y -> d_out (fp32).
//    grid (32,8,4). Row norms recomputed later by normalize_kernel.
// ---------------------------------------------------------------------------
__global__ __launch_bounds__(256) void pv_kernel(
    const u16* __restrict__ P, const u16* __restrict__ Vt,
    const float* __restrict__ x, float* __restrict__ y)
{
    __shared__ u16 As[128 * BK];
    __shared__ u16 Bs[128 * BK];
    const int b = blockIdx.z;
    const int tile_m = blockIdx.x * 128;           // query tile
    const int tile_n = blockIdx.y * 128;           // d tile
    const u16* Ab = P  + (size_t)b * S * S + (size_t)tile_m * S;
    const u16* Bv = Vt + (size_t)b * D * S + (size_t)tile_n * S;

    f32x4 acc[4][4];
#pragma unroll
    for (int i = 0; i < 4; ++i)
#pragma unroll
        for (int j = 0; j < 4; ++j) acc[i][j] = (f32x4)0.0f;

    gemm_nt_core<false>(Ab, Bv, S, As, Bs, acc);

    const int tid = threadIdx.x, lane = tid & 63, wid = tid >> 6;
    const int quad = lane >> 4, lrow = lane & 15;
    const int wm = (wid & 1) * 64, wn = (wid >> 1) * 64;

#pragma unroll
    for (int im = 0; im < 4; ++im)
#pragma unroll
        for (int r = 0; r < 4; ++r) {
            const int row = tile_m + wm + im * 16 + quad * 4 + r;   // query idx
            const size_t base = ((size_t)b * S + row) * D;
#pragma unroll
            for (int in = 0; in < 4; ++in) {
                const int col = tile_n + wn + in * 16 + lrow;       // d idx
                y[base + col] = acc[im][in][r] + x[base + col];
            }
        }
}

// ---------------------------------------------------------------------------
// 6) normalize rows of y (fp32) in place: block per row, 256 thr x float4.
// ---------------------------------------------------------------------------
__global__ __launch_bounds__(256) void normalize_kernel(float* __restrict__ y)
{
    const size_t row = blockIdx.x;
    const int tid = threadIdx.x;
    float4* p = (float4*)(y + row * D) + tid;

    float4 v = *p;
    float ss = v.x * v.x + v.y * v.y + v.z * v.z + v.w * v.w;
#pragma unroll
    for (int off = 32; off > 0; off >>= 1) ss += __shfl_xor(ss, off);

    __shared__ float red[4];
    const int wid = tid >> 6;
    if ((tid & 63) == 0) red[wid] = ss;
    __syncthreads();
    const float inv = rsqrtf(red[0] + red[1] + red[2] + red[3]);

    v.x *= inv; v.y *= inv; v.z *= inv; v.w *= inv;
    *p = v;
}

// ---------------------------------------------------------------------------
// Workspace layout (224 MiB total — V aliases the P region, which is only
// written after V is dead):
//   [0,32M)    Q   (fp16)
//   [32M,64M)  Kb  (fp16)
//   [64M,96M)  Vt  (fp16)
//   [96M,224M) P   (fp16; V lives in [96M,128M) until scores_kernel runs)
// ---------------------------------------------------------------------------
extern "C" void kernel_launch(void* const* d_in, const int* in_sizes, int n_in,
                              void* d_out, int out_size, void* d_ws, size_t ws_size,
                              hipStream_t stream) {
    const float* x  = (const float*)d_in[0];
    const float* Wq = (const float*)d_in[1];
    const float* Wk = (const float*)d_in[2];
    const float* Wv = (const float*)d_in[3];
    float* out = (float*)d_out;

    char* ws = (char*)d_ws;
    const size_t MB = 1ull << 20;
    u16* Q   = (u16*)(ws);
    u16* Kb  = (u16*)(ws + 32 * MB);
    u16* Vt  = (u16*)(ws + 64 * MB);
    u16* P   = (u16*)(ws + 96 * MB);
    u16* V   = P;                                  // alias: dead before P written

    dim3 blk(256);
    qkv_kernel    <<<dim3(NB * S / 128, D / 128, 3), blk, 0, stream>>>(x, Wq, Wk, Wv, Q, Kb, V);
    transpose_v   <<<dim3(NB * S / 64, D / 64), blk, 0, stream>>>(V, Vt);
    scores_kernel <<<dim3(S / 128, S / 128, NB), blk, 0, stream>>>(Q, Kb, P);
    softmax_kernel<<<dim3(NB * S), blk, 0, stream>>>(P);
    pv_kernel     <<<dim3(S / 128, D / 128, NB), blk, 0, stream>>>(P, Vt, x, out);
    normalize_kernel<<<dim3(NB * S), blk, 0, stream>>>(out);
}

// Round 5
// 678.437 us; speedup vs baseline: 1.1698x; 1.1698x over previous
//
#include <hip/hip_runtime.h>
#include <hip/hip_bf16.h>

typedef unsigned short u16;
typedef unsigned int   u32;
typedef _Float16 half8 __attribute__((ext_vector_type(8)));
typedef __attribute__((ext_vector_type(4))) float f32x4;

constexpr int NB = 4;        // batch
constexpr int S  = 4096;     // sequence
constexpr int D  = 1024;     // model dim
constexpr int BK = 32;       // GEMM K-tile (one mfma_16x16x32 per frag pair)

__device__ __forceinline__ u16 h2u(_Float16 h) {
    union { _Float16 h; u16 u; } v; v.h = h; return v.u;
}

// Async global->LDS, 16 B per lane. LDS destination must be wave-uniform
// base + lane*16 (our row-major 128xBK tile layout satisfies this).
__device__ __forceinline__ void async16(const void* g, void* l) {
    __builtin_amdgcn_global_load_lds(
        (const __attribute__((address_space(1))) unsigned int*)g,
        (__attribute__((address_space(3))) unsigned int*)l, 16, 0, 0);
}

// ---------------------------------------------------------------------------
// NT GEMM core, m97-style async staging: A [128 x K] fp16 row-major
// (pre-offset), B [128 x K] fp16 row-major (pre-offset). 128x128 tile,
// 256 threads = 4 waves (2x2), each wave 64x64 (4x4 mfma 16x16x32 f16).
// Fragment layouts (HW-verified, dtype-independent):
//   A: lane holds A[m=lane&15][k0 + (lane>>4)*8 + j]
//   B: lane holds B[n=lane&15][k0 + (lane>>4)*8 + j]
//   C: acc[r] = C[row=(lane>>4)*4+r][col=lane&15]
// K-loop: barrier / issue 4x global_load_lds / barrier(vmcnt drain) / mfma.
// ---------------------------------------------------------------------------
__device__ __forceinline__ void gemm_nt_async(
    const u16* __restrict__ A, const u16* __restrict__ B, int K,
    u16* As, u16* Bs, f32x4 acc[4][4])
{
    const int tid  = threadIdx.x;
    const int lane = tid & 63;
    const int wid  = tid >> 6;
    const int quad = lane >> 4;
    const int lrow = lane & 15;
    const int wm   = (wid & 1) * 64;
    const int wn   = (wid >> 1) * 64;

    // staging: wave w covers rows [w*32, w*32+32) of each 128xBK tile,
    // two 16-row instructions per matrix; lane l -> row r0, 16B col chunk cb.
    const int r0 = wid * 32 + (lane >> 2);     // 0..127 (16-row group per instr)
    const int cb = (lane & 3) * 8;             // col in elems: 0,8,16,24
    const u16* Ag0 = A + (size_t)r0 * K + cb;
    const u16* Ag1 = Ag0 + (size_t)16 * K;
    const u16* Bg0 = B + (size_t)r0 * K + cb;
    const u16* Bg1 = Bg0 + (size_t)16 * K;
    u16* Al0 = As + r0 * BK + cb;  u16* Al1 = Al0 + 16 * BK;
    u16* Bl0 = Bs + r0 * BK + cb;  u16* Bl1 = Bl0 + 16 * BK;

    const u16* AsR = As + (size_t)(wm + lrow) * BK + quad * 8;
    const u16* BsR = Bs + (size_t)(wn + lrow) * BK + quad * 8;

    for (int k0 = 0; k0 < K; k0 += BK) {
        __syncthreads();                       // prev iter's LDS reads done
        async16(Ag0 + k0, Al0);
        async16(Ag1 + k0, Al1);
        async16(Bg0 + k0, Bl0);
        async16(Bg1 + k0, Bl1);
        __syncthreads();                       // vmcnt(0) drain -> data in LDS
        half8 af[4], bf[4];
#pragma unroll
        for (int i = 0; i < 4; ++i) af[i] = *(const half8*)(AsR + i * 16 * BK);
#pragma unroll
        for (int i = 0; i < 4; ++i) bf[i] = *(const half8*)(BsR + i * 16 * BK);
#pragma unroll
        for (int im = 0; im < 4; ++im)
#pragma unroll
            for (int in = 0; in < 4; ++in)
                acc[im][in] = __builtin_amdgcn_mfma_f32_16x16x32_f16(
                    af[im], bf[in], acc[im][in], 0, 0, 0);
    }
}

// ---------------------------------------------------------------------------
// 0) fp32 -> fp16 cast, 8 elems/thread
// ---------------------------------------------------------------------------
__global__ __launch_bounds__(256) void cvt_kernel(
    const float* __restrict__ in, u16* __restrict__ out, int n8)
{
    const int i = blockIdx.x * 256 + threadIdx.x;
    if (i >= n8) return;
    const float4 a = *(const float4*)(in + (size_t)i * 8);
    const float4 b = *(const float4*)(in + (size_t)i * 8 + 4);
    half8 h;
    h[0] = (_Float16)a.x; h[1] = (_Float16)a.y;
    h[2] = (_Float16)a.z; h[3] = (_Float16)a.w;
    h[4] = (_Float16)b.x; h[5] = (_Float16)b.y;
    h[6] = (_Float16)b.z; h[7] = (_Float16)b.w;
    *(half8*)(out + (size_t)i * 8) = h;
}

// ---------------------------------------------------------------------------
// 1) QKV projection: out[s,e] = sum_d x16[s,d] * W16[e,d]  (NT, K=D)
// grid (NB*S/128=128, D/128=8, 3); z picks {Wq,Wk,Wv} -> {Q,K,V} (fp16)
// ---------------------------------------------------------------------------
__global__ __launch_bounds__(256) void qkv_kernel(
    const u16* __restrict__ x16, const u16* __restrict__ W16,
    u16* __restrict__ Q, u16* __restrict__ Kb, u16* __restrict__ V)
{
    __shared__ u16 As[128 * BK];
    __shared__ u16 Bs[128 * BK];
    const int tile_m = blockIdx.x * 128;
    const int tile_n = blockIdx.y * 128;
    const u16* W = W16 + (size_t)blockIdx.z * D * D;
    u16* out = (blockIdx.z == 0) ? Q : (blockIdx.z == 1) ? Kb : V;

    f32x4 acc[4][4];
#pragma unroll
    for (int i = 0; i < 4; ++i)
#pragma unroll
        for (int j = 0; j < 4; ++j) acc[i][j] = (f32x4)0.0f;

    gemm_nt_async(x16 + (size_t)tile_m * D, W + (size_t)tile_n * D, D, As, Bs, acc);

    const int tid = threadIdx.x, lane = tid & 63, wid = tid >> 6;
    const int quad = lane >> 4, lrow = lane & 15;
    const int wm = (wid & 1) * 64, wn = (wid >> 1) * 64;
#pragma unroll
    for (int im = 0; im < 4; ++im)
#pragma unroll
        for (int r = 0; r < 4; ++r) {
            const int row = tile_m + wm + im * 16 + quad * 4 + r;
#pragma unroll
            for (int in = 0; in < 4; ++in) {
                const int col = tile_n + wn + in * 16 + lrow;
                out[(size_t)row * D + col] = h2u((_Float16)acc[im][in][r]);
            }
        }
}

// ---------------------------------------------------------------------------
// 2) Transpose V [NB*S x D] -> Vt [NB][D][S] (64x64 LDS tiles, fp16 bits)
// ---------------------------------------------------------------------------
__global__ __launch_bounds__(256) void transpose_v(
    const u16* __restrict__ V, u16* __restrict__ Vt)
{
    __shared__ u16 t[64][72];                      // 144B row stride (16B-mult)
    const int sg = blockIdx.x * 64;                // global row (b,s)
    const int b  = sg >> 12;
    const int s0 = sg & (S - 1);
    const int e0 = blockIdx.y * 64;
    const int tid = threadIdx.x;
#pragma unroll
    for (int p = 0; p < 2; ++p) {
        const int v  = tid + 256 * p;              // 0..511
        const int sr = v >> 3, sc = (v & 7) * 8;
        half8 vec = *(const half8*)(V + (size_t)(sg + sr) * D + e0 + sc);
        *(half8*)&t[sr][sc] = vec;
    }
    __syncthreads();
#pragma unroll
    for (int p = 0; p < 2; ++p) {
        const int v  = tid + 256 * p;
        const int e  = v >> 3, s8 = (v & 7) * 8;
        u16 o[8];
#pragma unroll
        for (int j = 0; j < 8; ++j) o[j] = t[s8 + j][e];
        *(uint4*)(Vt + (size_t)b * D * S + (size_t)(e0 + e) * S + s0 + s8) = *(const uint4*)o;
    }
}

// ---------------------------------------------------------------------------
// 3) scores: P[b][q][k] = Q_b[q,:] . K_b[k,:]   (NT, K=D), grid (32,32,4)
// ---------------------------------------------------------------------------
__global__ __launch_bounds__(256) void scores_kernel(
    const u16* __restrict__ Q, const u16* __restrict__ Kb, u16* __restrict__ P)
{
    __shared__ u16 As[128 * BK];
    __shared__ u16 Bs[128 * BK];
    const int b = blockIdx.z;
    const int tile_m = blockIdx.x * 128;
    const int tile_n = blockIdx.y * 128;
    const u16* Ab = Q  + (size_t)b * S * D + (size_t)tile_m * D;
    const u16* Bv = Kb + (size_t)b * S * D + (size_t)tile_n * D;

    f32x4 acc[4][4];
#pragma unroll
    for (int i = 0; i < 4; ++i)
#pragma unroll
        for (int j = 0; j < 4; ++j) acc[i][j] = (f32x4)0.0f;

    gemm_nt_async(Ab, Bv, D, As, Bs, acc);

    u16* Pb = P + (size_t)b * S * S;
    const int tid = threadIdx.x, lane = tid & 63, wid = tid >> 6;
    const int quad = lane >> 4, lrow = lane & 15;
    const int wm = (wid & 1) * 64, wn = (wid >> 1) * 64;
#pragma unroll
    for (int im = 0; im < 4; ++im)
#pragma unroll
        for (int r = 0; r < 4; ++r) {
            const int row = tile_m + wm + im * 16 + quad * 4 + r;
#pragma unroll
            for (int in = 0; in < 4; ++in) {
                const int col = tile_n + wn + in * 16 + lrow;
                Pb[(size_t)row * S + col] = h2u((_Float16)acc[im][in][r]);
            }
        }
}

// ---------------------------------------------------------------------------
// 4) softmax over each row of P (4096 fp16), in place. 256 thr x 16 elems.
// ---------------------------------------------------------------------------
__global__ __launch_bounds__(256) void softmax_kernel(u16* __restrict__ P)
{
    const size_t row = blockIdx.x;                 // 0..NB*S-1 (flat: stride S)
    u16* p = P + row * S;
    const int tid = threadIdx.x;

    half8 h0 = *(const half8*)(p + tid * 16);
    half8 h1 = *(const half8*)(p + tid * 16 + 8);
    float v[16];
#pragma unroll
    for (int i = 0; i < 8; ++i) { v[i] = (float)h0[i]; v[8 + i] = (float)h1[i]; }

    float m = v[0];
#pragma unroll
    for (int i = 1; i < 16; ++i) m = fmaxf(m, v[i]);
#pragma unroll
    for (int off = 32; off > 0; off >>= 1) m = fmaxf(m, __shfl_xor(m, off));

    __shared__ float redm[4], reds[4];
    const int wid = tid >> 6;
    if ((tid & 63) == 0) redm[wid] = m;
    __syncthreads();
    m = fmaxf(fmaxf(redm[0], redm[1]), fmaxf(redm[2], redm[3]));

    float e[16], s = 0.f;
#pragma unroll
    for (int i = 0; i < 16; ++i) { e[i] = __expf(v[i] - m); s += e[i]; }
#pragma unroll
    for (int off = 32; off > 0; off >>= 1) s += __shfl_xor(s, off);
    if ((tid & 63) == 0) reds[wid] = s;
    __syncthreads();
    s = reds[0] + reds[1] + reds[2] + reds[3];
    const float inv = 1.0f / s;                    // s >= 1 always

#pragma unroll
    for (int i = 0; i < 8; ++i) {
        h0[i] = (_Float16)(e[i] * inv);
        h1[i] = (_Float16)(e[8 + i] * inv);
    }
    *(half8*)(p + tid * 16)     = h0;
    *(half8*)(p + tid * 16 + 8) = h1;
}

// ---------------------------------------------------------------------------
// 5) PV: y[b,q,d] = sum_k P[b,q,k]*Vt[b,d,k] + x[b,q,d]; y -> d_out (fp32).
//    grid (32,8,4). Row norms recomputed later by normalize_kernel.
// ---------------------------------------------------------------------------
__global__ __launch_bounds__(256) void pv_kernel(
    const u16* __restrict__ P, const u16* __restrict__ Vt,
    const float* __restrict__ x, float* __restrict__ y)
{
    __shared__ u16 As[128 * BK];
    __shared__ u16 Bs[128 * BK];
    const int b = blockIdx.z;
    const int tile_m = blockIdx.x * 128;           // query tile
    const int tile_n = blockIdx.y * 128;           // d tile
    const u16* Ab = P  + (size_t)b * S * S + (size_t)tile_m * S;
    const u16* Bv = Vt + (size_t)b * D * S + (size_t)tile_n * S;

    f32x4 acc[4][4];
#pragma unroll
    for (int i = 0; i < 4; ++i)
#pragma unroll
        for (int j = 0; j < 4; ++j) acc[i][j] = (f32x4)0.0f;

    gemm_nt_async(Ab, Bv, S, As, Bs, acc);

    const int tid = threadIdx.x, lane = tid & 63, wid = tid >> 6;
    const int quad = lane >> 4, lrow = lane & 15;
    const int wm = (wid & 1) * 64, wn = (wid >> 1) * 64;

#pragma unroll
    for (int im = 0; im < 4; ++im)
#pragma unroll
        for (int r = 0; r < 4; ++r) {
            const int row = tile_m + wm + im * 16 + quad * 4 + r;   // query idx
            const size_t base = ((size_t)b * S + row) * D;
#pragma unroll
            for (int in = 0; in < 4; ++in) {
                const int col = tile_n + wn + in * 16 + lrow;       // d idx
                y[base + col] = acc[im][in][r] + x[base + col];
            }
        }
}

// ---------------------------------------------------------------------------
// 6) normalize rows of y (fp32) in place: block per row, 256 thr x float4.
// ---------------------------------------------------------------------------
__global__ __launch_bounds__(256) void normalize_kernel(float* __restrict__ y)
{
    const size_t row = blockIdx.x;
    const int tid = threadIdx.x;
    float4* p = (float4*)(y + row * D) + tid;

    float4 v = *p;
    float ss = v.x * v.x + v.y * v.y + v.z * v.z + v.w * v.w;
#pragma unroll
    for (int off = 32; off > 0; off >>= 1) ss += __shfl_xor(ss, off);

    __shared__ float red[4];
    const int wid = tid >> 6;
    if ((tid & 63) == 0) red[wid] = ss;
    __syncthreads();
    const float inv = rsqrtf(red[0] + red[1] + red[2] + red[3]);

    v.x *= inv; v.y *= inv; v.z *= inv; v.w *= inv;
    *p = v;
}

// ---------------------------------------------------------------------------
// Workspace layout (224 MiB total, aggressive aliasing):
//   [0,32M)     Q   (fp16)
//   [32M,64M)   Kb  (fp16)
//   [64M,96M)   Vt  (fp16)    <- x16 lives here until transpose_v runs
//   [96M,224M)  P   (fp16)    <- V in [96M,128M) until scores runs;
//                                W16 (6 MiB) in [218M,224M) until scores runs
// Lifetimes: cvt writes x16,W16 -> qkv reads x16,W16, writes Q,Kb,V ->
// transpose_v reads V, overwrites x16 region with Vt -> scores reads Q,Kb,
// overwrites V+W16 regions with P -> softmax -> pv -> normalize.
// ---------------------------------------------------------------------------
extern "C" void kernel_launch(void* const* d_in, const int* in_sizes, int n_in,
                              void* d_out, int out_size, void* d_ws, size_t ws_size,
                              hipStream_t stream) {
    const float* x  = (const float*)d_in[0];
    const float* Wq = (const float*)d_in[1];
    const float* Wk = (const float*)d_in[2];
    const float* Wv = (const float*)d_in[3];
    float* out = (float*)d_out;

    char* ws = (char*)d_ws;
    const size_t MB = 1ull << 20;
    u16* Q   = (u16*)(ws);
    u16* Kb  = (u16*)(ws + 32 * MB);
    u16* Vt  = (u16*)(ws + 64 * MB);
    u16* P   = (u16*)(ws + 96 * MB);
    u16* V   = P;                                  // alias: dead before P written
    u16* x16 = Vt;                                 // alias: dead before Vt written
    u16* W16 = (u16*)(ws + 218 * MB);              // alias into P tail: dead before
                                                   // scores writes there

    dim3 blk(256);
    cvt_kernel <<<dim3(NB * S * D / 8 / 256), blk, 0, stream>>>(x,  x16, NB * S * D / 8);
    cvt_kernel <<<dim3(D * D / 8 / 256), blk, 0, stream>>>(Wq, W16,             D * D / 8);
    cvt_kernel <<<dim3(D * D / 8 / 256), blk, 0, stream>>>(Wk, W16 + (size_t)D * D, D * D / 8);
    cvt_kernel <<<dim3(D * D / 8 / 256), blk, 0, stream>>>(Wv, W16 + (size_t)2 * D * D, D * D / 8);

    qkv_kernel    <<<dim3(NB * S / 128, D / 128, 3), blk, 0, stream>>>(x16, W16, Q, Kb, V);
    transpose_v   <<<dim3(NB * S / 64, D / 64), blk, 0, stream>>>(V, Vt);
    scores_kernel <<<dim3(S / 128, S / 128, NB), blk, 0, stream>>>(Q, Kb, P);
    softmax_kernel<<<dim3(NB * S), blk, 0, stream>>>(P);
    pv_kernel     <<<dim3(S / 128, D / 128, NB), blk, 0, stream>>>(P, Vt, x, out);
    normalize_kernel<<<dim3(NB * S), blk, 0, stream>>>(out);
}

// Round 6
// 603.438 us; speedup vs baseline: 1.3152x; 1.1243x over previous
//
#include <hip/hip_runtime.h>
#include <hip/hip_bf16.h>

typedef unsigned short u16;
typedef unsigned int   u32;
typedef _Float16 half8 __attribute__((ext_vector_type(8)));
typedef __attribute__((ext_vector_type(4))) float f32x4;

constexpr int NB = 4;        // batch
constexpr int S  = 4096;     // sequence
constexpr int D  = 1024;     // model dim
constexpr int BK = 64;       // GEMM K-tile (2 mfma K-halves; 32 MFMA / barrier)

__device__ __forceinline__ u16 h2u(_Float16 h) {
    union { _Float16 h; u16 u; } v; v.h = h; return v.u;
}

// Async global->LDS, 16 B per lane. LDS destination is wave-uniform
// base + lane*16 (lane-linear chunk order).
__device__ __forceinline__ void async16(const void* g, void* l) {
    __builtin_amdgcn_global_load_lds(
        (const __attribute__((address_space(1))) unsigned int*)g,
        (__attribute__((address_space(3))) unsigned int*)l, 16, 0, 0);
}

// ---------------------------------------------------------------------------
// NT GEMM core: A [128 x K] fp16 row-major (pre-offset), B [128 x K] fp16
// row-major (pre-offset). 128x128 tile, 256 threads = 4 waves (2x2), each
// wave 64x64 (4x4 mfma 16x16x32 f16, 2 K-halves per BK=64 tile).
//
// LDS layout (per matrix): 128 rows x 8 chunks of 16B (128 B row = full bank
// period). XOR swizzle: global chunk gc of row r stored at chunk gc ^ (r&7).
// Since global_load_lds forces LDS position = lane-linear, the swizzle is
// applied to the SOURCE address: lane l = (rl<<3)|cl loads global chunk
// cl ^ rl. Read of (row, chunk q) -> LDS chunk q ^ (row&7): 16 same-quad
// lanes spread over all 8 bank groups (2-way = free, m136).
//
// Fragment layouts (HW-verified, dtype-independent):
//   A: lane holds A[m=lane&15][k0 + kk*32 + (lane>>4)*8 + j]
//   B: lane holds B[n=lane&15][k0 + kk*32 + (lane>>4)*8 + j]
//   C: acc[r] = C[row=(lane>>4)*4+r][col=lane&15]
// ---------------------------------------------------------------------------
__device__ __forceinline__ void gemm_nt_async(
    const u16* __restrict__ A, const u16* __restrict__ B, int K,
    u16* As, u16* Bs, f32x4 acc[4][4])
{
    const int tid  = threadIdx.x;
    const int lane = tid & 63;
    const int wid  = tid >> 6;
    const int quad = lane >> 4;
    const int lrow = lane & 15;
    const int s7   = lrow & 7;
    const int wm   = (wid & 1) * 64;
    const int wn   = (wid >> 1) * 64;

    // --- staging addressing (swizzled source, lane-linear LDS dest) ---
    const int rl = lane >> 3;                  // 0..7  row within 8-row group
    const int cl = lane & 7;                   // 0..7  LDS chunk position
    const int gc = cl ^ rl;                    // swizzled global chunk
    const int row0 = wid * 32 + rl;            // instr j adds 8 rows
    const u16* Ag = A + (size_t)row0 * K + gc * 8;
    const u16* Bg = B + (size_t)row0 * K + gc * 8;
    u16* Al = As + ((size_t)wid * 256 + lane) * 8;   // chunk p0 = wid*256+lane
    u16* Bl = Bs + ((size_t)wid * 256 + lane) * 8;

    for (int k0 = 0; k0 < K; k0 += BK) {
        __syncthreads();                       // prev iter's LDS reads done
#pragma unroll
        for (int j = 0; j < 4; ++j)
            async16(Ag + k0 + (size_t)j * 8 * K, Al + j * 512);
#pragma unroll
        for (int j = 0; j < 4; ++j)
            async16(Bg + k0 + (size_t)j * 8 * K, Bl + j * 512);
        __syncthreads();                       // vmcnt(0) drain -> data in LDS
#pragma unroll
        for (int kk = 0; kk < 2; ++kk) {
            half8 af[4], bf[4];
#pragma unroll
            for (int i = 0; i < 4; ++i)
                af[i] = *(const half8*)(As + (wm + i * 16 + lrow) * 64
                                           + (((kk * 4 + quad) ^ s7) * 8));
#pragma unroll
            for (int i = 0; i < 4; ++i)
                bf[i] = *(const half8*)(Bs + (wn + i * 16 + lrow) * 64
                                           + (((kk * 4 + quad) ^ s7) * 8));
#pragma unroll
            for (int im = 0; im < 4; ++im)
#pragma unroll
                for (int in = 0; in < 4; ++in)
                    acc[im][in] = __builtin_amdgcn_mfma_f32_16x16x32_f16(
                        af[im], bf[in], acc[im][in], 0, 0, 0);
        }
    }
}

// ---------------------------------------------------------------------------
// 0) fp32 -> fp16 cast, 8 elems/thread
// ---------------------------------------------------------------------------
__global__ __launch_bounds__(256) void cvt_kernel(
    const float* __restrict__ in, u16* __restrict__ out, int n8)
{
    const int i = blockIdx.x * 256 + threadIdx.x;
    if (i >= n8) return;
    const float4 a = *(const float4*)(in + (size_t)i * 8);
    const float4 b = *(const float4*)(in + (size_t)i * 8 + 4);
    half8 h;
    h[0] = (_Float16)a.x; h[1] = (_Float16)a.y;
    h[2] = (_Float16)a.z; h[3] = (_Float16)a.w;
    h[4] = (_Float16)b.x; h[5] = (_Float16)b.y;
    h[6] = (_Float16)b.z; h[7] = (_Float16)b.w;
    *(half8*)(out + (size_t)i * 8) = h;
}

// ---------------------------------------------------------------------------
// 1) QKV projection: out[s,e] = sum_d x16[s,d] * W16[e,d]  (NT, K=D)
// grid (NB*S/128=128, D/128=8, 3); z picks {Wq,Wk,Wv} -> {Q,K,V} (fp16)
// ---------------------------------------------------------------------------
__global__ __launch_bounds__(256) void qkv_kernel(
    const u16* __restrict__ x16, const u16* __restrict__ W16,
    u16* __restrict__ Q, u16* __restrict__ Kb, u16* __restrict__ V)
{
    __shared__ __align__(16) u16 As[128 * BK];
    __shared__ __align__(16) u16 Bs[128 * BK];
    const int tile_m = blockIdx.x * 128;
    const int tile_n = blockIdx.y * 128;
    const u16* W = W16 + (size_t)blockIdx.z * D * D;
    u16* out = (blockIdx.z == 0) ? Q : (blockIdx.z == 1) ? Kb : V;

    f32x4 acc[4][4];
#pragma unroll
    for (int i = 0; i < 4; ++i)
#pragma unroll
        for (int j = 0; j < 4; ++j) acc[i][j] = (f32x4)0.0f;

    gemm_nt_async(x16 + (size_t)tile_m * D, W + (size_t)tile_n * D, D, As, Bs, acc);

    const int tid = threadIdx.x, lane = tid & 63, wid = tid >> 6;
    const int quad = lane >> 4, lrow = lane & 15;
    const int wm = (wid & 1) * 64, wn = (wid >> 1) * 64;
#pragma unroll
    for (int im = 0; im < 4; ++im)
#pragma unroll
        for (int r = 0; r < 4; ++r) {
            const int row = tile_m + wm + im * 16 + quad * 4 + r;
#pragma unroll
            for (int in = 0; in < 4; ++in) {
                const int col = tile_n + wn + in * 16 + lrow;
                out[(size_t)row * D + col] = h2u((_Float16)acc[im][in][r]);
            }
        }
}

// ---------------------------------------------------------------------------
// 2) Transpose V [NB*S x D] -> Vt [NB][D][S] (64x64 LDS tiles, fp16 bits)
// ---------------------------------------------------------------------------
__global__ __launch_bounds__(256) void transpose_v(
    const u16* __restrict__ V, u16* __restrict__ Vt)
{
    __shared__ u16 t[64][72];                      // 144B row stride (16B-mult)
    const int sg = blockIdx.x * 64;                // global row (b,s)
    const int b  = sg >> 12;
    const int s0 = sg & (S - 1);
    const int e0 = blockIdx.y * 64;
    const int tid = threadIdx.x;
#pragma unroll
    for (int p = 0; p < 2; ++p) {
        const int v  = tid + 256 * p;              // 0..511
        const int sr = v >> 3, sc = (v & 7) * 8;
        half8 vec = *(const half8*)(V + (size_t)(sg + sr) * D + e0 + sc);
        *(half8*)&t[sr][sc] = vec;
    }
    __syncthreads();
#pragma unroll
    for (int p = 0; p < 2; ++p) {
        const int v  = tid + 256 * p;
        const int e  = v >> 3, s8 = (v & 7) * 8;
        u16 o[8];
#pragma unroll
        for (int j = 0; j < 8; ++j) o[j] = t[s8 + j][e];
        *(uint4*)(Vt + (size_t)b * D * S + (size_t)(e0 + e) * S + s0 + s8) = *(const uint4*)o;
    }
}

// ---------------------------------------------------------------------------
// 3) scores: P[b][q][k] = Q_b[q,:] . K_b[k,:]   (NT, K=D), grid (32,32,4)
// ---------------------------------------------------------------------------
__global__ __launch_bounds__(256) void scores_kernel(
    const u16* __restrict__ Q, const u16* __restrict__ Kb, u16* __restrict__ P)
{
    __shared__ __align__(16) u16 As[128 * BK];
    __shared__ __align__(16) u16 Bs[128 * BK];
    const int b = blockIdx.z;
    const int tile_m = blockIdx.x * 128;
    const int tile_n = blockIdx.y * 128;
    const u16* Ab = Q  + (size_t)b * S * D + (size_t)tile_m * D;
    const u16* Bv = Kb + (size_t)b * S * D + (size_t)tile_n * D;

    f32x4 acc[4][4];
#pragma unroll
    for (int i = 0; i < 4; ++i)
#pragma unroll
        for (int j = 0; j < 4; ++j) acc[i][j] = (f32x4)0.0f;

    gemm_nt_async(Ab, Bv, D, As, Bs, acc);

    u16* Pb = P + (size_t)b * S * S;
    const int tid = threadIdx.x, lane = tid & 63, wid = tid >> 6;
    const int quad = lane >> 4, lrow = lane & 15;
    const int wm = (wid & 1) * 64, wn = (wid >> 1) * 64;
#pragma unroll
    for (int im = 0; im < 4; ++im)
#pragma unroll
        for (int r = 0; r < 4; ++r) {
            const int row = tile_m + wm + im * 16 + quad * 4 + r;
#pragma unroll
            for (int in = 0; in < 4; ++in) {
                const int col = tile_n + wn + in * 16 + lrow;
                Pb[(size_t)row * S + col] = h2u((_Float16)acc[im][in][r]);
            }
        }
}

// ---------------------------------------------------------------------------
// 4) softmax over each row of P (4096 fp16), in place. 256 thr x 16 elems.
// ---------------------------------------------------------------------------
__global__ __launch_bounds__(256) void softmax_kernel(u16* __restrict__ P)
{
    const size_t row = blockIdx.x;                 // 0..NB*S-1 (flat: stride S)
    u16* p = P + row * S;
    const int tid = threadIdx.x;

    half8 h0 = *(const half8*)(p + tid * 16);
    half8 h1 = *(const half8*)(p + tid * 16 + 8);
    float v[16];
#pragma unroll
    for (int i = 0; i < 8; ++i) { v[i] = (float)h0[i]; v[8 + i] = (float)h1[i]; }

    float m = v[0];
#pragma unroll
    for (int i = 1; i < 16; ++i) m = fmaxf(m, v[i]);
#pragma unroll
    for (int off = 32; off > 0; off >>= 1) m = fmaxf(m, __shfl_xor(m, off));

    __shared__ float redm[4], reds[4];
    const int wid = tid >> 6;
    if ((tid & 63) == 0) redm[wid] = m;
    __syncthreads();
    m = fmaxf(fmaxf(redm[0], redm[1]), fmaxf(redm[2], redm[3]));

    float e[16], s = 0.f;
#pragma unroll
    for (int i = 0; i < 16; ++i) { e[i] = __expf(v[i] - m); s += e[i]; }
#pragma unroll
    for (int off = 32; off > 0; off >>= 1) s += __shfl_xor(s, off);
    if ((tid & 63) == 0) reds[wid] = s;
    __syncthreads();
    s = reds[0] + reds[1] + reds[2] + reds[3];
    const float inv = 1.0f / s;                    // s >= 1 always

#pragma unroll
    for (int i = 0; i < 8; ++i) {
        h0[i] = (_Float16)(e[i] * inv);
        h1[i] = (_Float16)(e[8 + i] * inv);
    }
    *(half8*)(p + tid * 16)     = h0;
    *(half8*)(p + tid * 16 + 8) = h1;
}

// ---------------------------------------------------------------------------
// 5) PV: y[b,q,d] = sum_k P[b,q,k]*Vt[b,d,k] + x[b,q,d]; y -> d_out (fp32).
//    grid (32,8,4). Row norms recomputed later by normalize_kernel.
// ---------------------------------------------------------------------------
__global__ __launch_bounds__(256) void pv_kernel(
    const u16* __restrict__ P, const u16* __restrict__ Vt,
    const float* __restrict__ x, float* __restrict__ y)
{
    __shared__ __align__(16) u16 As[128 * BK];
    __shared__ __align__(16) u16 Bs[128 * BK];
    const int b = blockIdx.z;
    const int tile_m = blockIdx.x * 128;           // query tile
    const int tile_n = blockIdx.y * 128;           // d tile
    const u16* Ab = P  + (size_t)b * S * S + (size_t)tile_m * S;
    const u16* Bv = Vt + (size_t)b * D * S + (size_t)tile_n * S;

    f32x4 acc[4][4];
#pragma unroll
    for (int i = 0; i < 4; ++i)
#pragma unroll
        for (int j = 0; j < 4; ++j) acc[i][j] = (f32x4)0.0f;

    gemm_nt_async(Ab, Bv, S, As, Bs, acc);

    const int tid = threadIdx.x, lane = tid & 63, wid = tid >> 6;
    const int quad = lane >> 4, lrow = lane & 15;
    const int wm = (wid & 1) * 64, wn = (wid >> 1) * 64;

#pragma unroll
    for (int im = 0; im < 4; ++im)
#pragma unroll
        for (int r = 0; r < 4; ++r) {
            const int row = tile_m + wm + im * 16 + quad * 4 + r;   // query idx
            const size_t base = ((size_t)b * S + row) * D;
#pragma unroll
            for (int in = 0; in < 4; ++in) {
                const int col = tile_n + wn + in * 16 + lrow;       // d idx
                y[base + col] = acc[im][in][r] + x[base + col];
            }
        }
}

// ---------------------------------------------------------------------------
// 6) normalize rows of y (fp32) in place: block per row, 256 thr x float4.
// ---------------------------------------------------------------------------
__global__ __launch_bounds__(256) void normalize_kernel(float* __restrict__ y)
{
    const size_t row = blockIdx.x;
    const int tid = threadIdx.x;
    float4* p = (float4*)(y + row * D) + tid;

    float4 v = *p;
    float ss = v.x * v.x + v.y * v.y + v.z * v.z + v.w * v.w;
#pragma unroll
    for (int off = 32; off > 0; off >>= 1) ss += __shfl_xor(ss, off);

    __shared__ float red[4];
    const int wid = tid >> 6;
    if ((tid & 63) == 0) red[wid] = ss;
    __syncthreads();
    const float inv = rsqrtf(red[0] + red[1] + red[2] + red[3]);

    v.x *= inv; v.y *= inv; v.z *= inv; v.w *= inv;
    *p = v;
}

// ---------------------------------------------------------------------------
// Workspace layout (224 MiB total, aggressive aliasing):
//   [0,32M)     Q   (fp16)
//   [32M,64M)   Kb  (fp16)
//   [64M,96M)   Vt  (fp16)    <- x16 lives here until transpose_v runs
//   [96M,224M)  P   (fp16)    <- V in [96M,128M) until scores runs;
//                                W16 (6 MiB) in [218M,224M) until scores runs
// ---------------------------------------------------------------------------
extern "C" void kernel_launch(void* const* d_in, const int* in_sizes, int n_in,
                              void* d_out, int out_size, void* d_ws, size_t ws_size,
                              hipStream_t stream) {
    const float* x  = (const float*)d_in[0];
    const float* Wq = (const float*)d_in[1];
    const float* Wk = (const float*)d_in[2];
    const float* Wv = (const float*)d_in[3];
    float* out = (float*)d_out;

    char* ws = (char*)d_ws;
    const size_t MB = 1ull << 20;
    u16* Q   = (u16*)(ws);
    u16* Kb  = (u16*)(ws + 32 * MB);
    u16* Vt  = (u16*)(ws + 64 * MB);
    u16* P   = (u16*)(ws + 96 * MB);
    u16* V   = P;                                  // alias: dead before P written
    u16* x16 = Vt;                                 // alias: dead before Vt written
    u16* W16 = (u16*)(ws + 218 * MB);              // alias into P tail: dead before
                                                   // scores writes there

    dim3 blk(256);
    cvt_kernel <<<dim3(NB * S * D / 8 / 256), blk, 0, stream>>>(x,  x16, NB * S * D / 8);
    cvt_kernel <<<dim3(D * D / 8 / 256), blk, 0, stream>>>(Wq, W16,             D * D / 8);
    cvt_kernel <<<dim3(D * D / 8 / 256), blk, 0, stream>>>(Wk, W16 + (size_t)D * D, D * D / 8);
    cvt_kernel <<<dim3(D * D / 8 / 256), blk, 0, stream>>>(Wv, W16 + (size_t)2 * D * D, D * D / 8);

    qkv_kernel    <<<dim3(NB * S / 128, D / 128, 3), blk, 0, stream>>>(x16, W16, Q, Kb, V);
    transpose_v   <<<dim3(NB * S / 64, D / 64), blk, 0, stream>>>(V, Vt);
    scores_kernel <<<dim3(S / 128, S / 128, NB), blk, 0, stream>>>(Q, Kb, P);
    softmax_kernel<<<dim3(NB * S), blk, 0, stream>>>(P);
    pv_kernel     <<<dim3(S / 128, D / 128, NB), blk, 0, stream>>>(P, Vt, x, out);
    normalize_kernel<<<dim3(NB * S), blk, 0, stream>>>(out);
}